// Round 15
// baseline (154.769 us; speedup 1.0000x reference)
//
#include <hip/hip_runtime.h>
#include <hip/hip_bf16.h>
#include <math.h>

#define D_MODEL 1024
#define N_HEADS 16
#define D_K     64
#define BATCH   2
#define SEQ     2048
#define M_TOTAL (BATCH * SEQ)   // 4096

typedef __attribute__((ext_vector_type(8))) short short8;    // 8 bf16 = 4 VGPR
typedef __attribute__((ext_vector_type(4))) float f32x4;
typedef __attribute__((ext_vector_type(16))) float f32x16;

__device__ __forceinline__ ushort f2bf(float f) {
    __hip_bfloat16 h = __float2bfloat16(f);
    union { __hip_bfloat16 h; ushort u; } c; c.h = h; return c.u;
}

// packed bf16 convert (RNE on gfx950): lo = cvt(a), hi = cvt(b)
__device__ __forceinline__ uint cvtpk(float a, float b) {
    uint r;
    asm("v_cvt_pk_bf16_f32 %0, %1, %2" : "=v"(r) : "v"(a), "v"(b));
    return r;
}

__device__ __forceinline__ void gload_lds16(const void* g, void* l) {
    __builtin_amdgcn_global_load_lds(
        (const __attribute__((address_space(1))) void*)g,
        (__attribute__((address_space(3))) void*)l, 16, 0, 0);
}

// v_permlane32_swap_b32 vdst, vsrc — exchange diagonal probed at runtime.
__device__ __forceinline__ void plswap(uint& a, uint& b) {
    asm volatile("v_permlane32_swap_b32 %0, %1" : "+v"(a), "+v"(b));
}

// ---------------------------------------------------------------------------
// Fused f32 -> bf16 cast, 8 floats/thread. Wq is pre-scaled by
// 0.125*log2(e) (exact fold: s*(x@Wq^T) = x@(s*Wq)^T), so the QKV GEMM
// epilogue is scale-free and branch-light.
// 4096 blocks: x = 0..2047, Wq 2048..2559, Wk ..3071, Wv ..3583, Wo ..4095.
// ---------------------------------------------------------------------------
__global__ __launch_bounds__(256) void cast_all(const float* __restrict__ x,
                                                const float* __restrict__ Wq,
                                                const float* __restrict__ Wk,
                                                const float* __restrict__ Wv,
                                                const float* __restrict__ Wo,
                                                ushort* __restrict__ xb,
                                                ushort* __restrict__ wqkv,
                                                ushort* __restrict__ wob)
{
    const int bi = blockIdx.x;
    const float* src; ushort* dst; int blk;
    float scale = 1.0f;
    const int NW = D_MODEL * D_MODEL;  // 1M
    if (bi < 2048)      { src = x;  dst = xb;            blk = bi; }
    else if (bi < 2560) { src = Wq; dst = wqkv;          blk = bi - 2048;
                          scale = 0.125f * 1.44269504088896f; }
    else if (bi < 3072) { src = Wk; dst = wqkv + NW;     blk = bi - 2560; }
    else if (bi < 3584) { src = Wv; dst = wqkv + 2 * NW; blk = bi - 3072; }
    else                { src = Wo; dst = wob;           blk = bi - 3584; }
    const int i = blk * 2048 + threadIdx.x * 8;
    float4 a = *(const float4*)&src[i];
    float4 b = *(const float4*)&src[i + 4];
    uint4 o;
    o.x = cvtpk(a.x * scale, a.y * scale);
    o.y = cvtpk(a.z * scale, a.w * scale);
    o.z = cvtpk(b.x * scale, b.y * scale);
    o.w = cvtpk(b.z * scale, b.w * scale);
    *(uint4*)&dst[i] = o;
}

// ---------------------------------------------------------------------------
// QKV GEMM: C = A(M,K) * B(N,K)^T, 128x128 tile, BK=32, 256 thr (4 waves),
// global_load_lds w=16, double-buffered LDS, vmcnt-before-barrier prefetch,
// bijective XCD swizzle. Epilogue:
//   n0 < 2048 (q/k): scalar scatter to bf16 [B,H,S,Dk] (scale pre-folded)
//   n0 >= 2048 (v):  acc -> LDS [col][row] bf16 (32 KB, XOR swizzle) ->
//                    fully coalesced dwordx4 stores to [B,H,Dk,S].
// ---------------------------------------------------------------------------
__global__ __launch_bounds__(256) void gemm_qkv(const ushort* __restrict__ A,
                                                const ushort* __restrict__ B,
                                                ushort* __restrict__ q,
                                                ushort* __restrict__ k,
                                                ushort* __restrict__ v,
                                                int M, int N, int K)
{
    __shared__ ushort SH[16384];   // As = SH[0..8191] (2 bufs), Bs = SH[8192..]

    const int tid = threadIdx.x;
    const int lane = tid & 63;
    const int w = tid >> 6;
    const int li = lane & 15;
    const int kgl = lane >> 4;

    // XCD-aware bijective swizzle (nwg % 8 == 0)
    const int nwg = gridDim.x * gridDim.y;
    const int flat = blockIdx.y * gridDim.x + blockIdx.x;
    const int cpx = nwg >> 3;
    const int swz = (flat & 7) * cpx + (flat >> 3);
    const int m0 = (swz / gridDim.x) * 128;
    const int n0 = (swz % gridDim.x) * 128;

    const int wr = (w >> 1) * 64;
    const int wc = (w & 1) * 64;

    f32x4 acc[4][4] = {};

    const int s1 = tid, s2 = tid + 256;
    const ushort* ga1 = &A[(size_t)(m0 + (s1 & 127)) * K + (s1 >> 7) * 8];
    const ushort* ga2 = &A[(size_t)(m0 + (s2 & 127)) * K + (s2 >> 7) * 8];
    const ushort* gb1 = &B[(size_t)(n0 + (s1 & 127)) * K + (s1 >> 7) * 8];
    const ushort* gb2 = &B[(size_t)(n0 + (s2 & 127)) * K + (s2 >> 7) * 8];

    const int NT = K / 32;
    gload_lds16(ga1, &SH[0 + s1 * 8]);
    gload_lds16(ga2, &SH[0 + s2 * 8]);
    gload_lds16(gb1, &SH[8192 + s1 * 8]);
    gload_lds16(gb2, &SH[8192 + s2 * 8]);

    for (int t = 0; t < NT; ++t) {
        const int cur = t & 1;
        asm volatile("s_waitcnt vmcnt(0)" ::: "memory");
        __syncthreads();
        if (t + 1 < NT) {
            const int kb = (t + 1) * 32;
            const int nxt = cur ^ 1;
            gload_lds16(ga1 + kb, &SH[nxt * 4096 + s1 * 8]);
            gload_lds16(ga2 + kb, &SH[nxt * 4096 + s2 * 8]);
            gload_lds16(gb1 + kb, &SH[8192 + nxt * 4096 + s1 * 8]);
            gload_lds16(gb2 + kb, &SH[8192 + nxt * 4096 + s2 * 8]);
        }
        short8 af[4], bf_[4];
#pragma unroll
        for (int m = 0; m < 4; ++m)
            af[m] = *(const short8*)&SH[cur * 4096 + (kgl * 128 + wr + m * 16 + li) * 8];
#pragma unroll
        for (int n = 0; n < 4; ++n)
            bf_[n] = *(const short8*)&SH[8192 + cur * 4096 + (kgl * 128 + wc + n * 16 + li) * 8];
#pragma unroll
        for (int m = 0; m < 4; ++m)
#pragma unroll
            for (int n = 0; n < 4; ++n)
                acc[m][n] = __builtin_amdgcn_mfma_f32_16x16x32_bf16(
                    af[m], bf_[n], acc[m][n], 0, 0, 0);
    }

    if (n0 < 2048) {
        // q/k scatter; dst is block-uniform (128 | 1024), scale pre-folded
        ushort* const dst = (n0 < 1024) ? q : k;
#pragma unroll
        for (int m = 0; m < 4; ++m) {
            const int Rb = m0 + wr + m * 16 + kgl * 4;
#pragma unroll
            for (int n = 0; n < 4; ++n) {
                const int rem = (n0 + wc + n * 16 + li) & 1023;
                const int h = rem >> 6, dk = rem & 63;
#pragma unroll
                for (int r = 0; r < 4; ++r) {
                    const int R = Rb + r;
                    const int b = R >> 11, s = R & 2047;
                    const int bh = b * N_HEADS + h;
                    dst[((size_t)bh * SEQ + s) * D_K + dk] = f2bf(acc[m][n][r]);
                }
            }
        }
    } else {
        // v: LDS transpose (reuse the 32KB staging pool) + coalesced stores
        __syncthreads();   // all waves done with K-loop LDS reads
#pragma unroll
        for (int m = 0; m < 4; ++m) {
            const int row0 = wr + m * 16 + kgl * 4;   // local C row (s)
#pragma unroll
            for (int n = 0; n < 4; ++n) {
                const int col = wc + n * 16 + li;     // local C col (dk')
                uint2 pv;
                pv.x = cvtpk(acc[m][n][0], acc[m][n][1]);
                pv.y = cvtpk(acc[m][n][2], acc[m][n][3]);
                const int byte = (col * 256 + row0 * 2) ^ ((col & 7) << 5);
                *(uint2*)((char*)SH + byte) = pv;
            }
        }
        __syncthreads();
        const int b = m0 >> 11, s0 = m0 & 2047;
        const int lsl = tid & 15;       // s sub-chunk (16B)
        const int crow = tid >> 4;      // 0..15
#pragma unroll
        for (int it = 0; it < 8; ++it) {
            const int c = it * 16 + crow;                 // local col (dk')
            const int rem = (n0 & 1023) + c;
            const int h = rem >> 6, dk = rem & 63;
            const int byte = (c * 256 + lsl * 16) ^ ((c & 7) << 5);
            uint4 val = *(uint4*)((char*)SH + byte);
            ushort* vp = v + ((size_t)(b * N_HEADS + h) * D_K + dk) * SEQ + s0 + lsl * 8;
            *(uint4*)vp = val;
        }
    }
}

// ---------------------------------------------------------------------------
// Output GEMM: C(fp32) = A(M,K) * B(N,K)^T. 64x128 tile, BK=32, 256 thr
// (4 waves of 64x32): grid 8x64 = 512 blocks = 2 blocks/CU.
// ---------------------------------------------------------------------------
__global__ __launch_bounds__(256) void gemm_out(const ushort* __restrict__ A,
                                                const ushort* __restrict__ B,
                                                float* __restrict__ C,
                                                int M, int N, int K)
{
    __shared__ ushort As[2][4 * 64 * 8];     // 4 KB per buf
    __shared__ ushort Bs[2][4 * 128 * 8];    // 8 KB per buf

    const int tid = threadIdx.x;
    const int lane = tid & 63;
    const int wv = tid >> 6;          // wave 0..3 -> n-col strip of 32
    const int li = lane & 15;
    const int kgl = lane >> 4;

    const int nwg = gridDim.x * gridDim.y;
    const int flat = blockIdx.y * gridDim.x + blockIdx.x;
    const int cpx = nwg >> 3;
    const int swz = (flat & 7) * cpx + (flat >> 3);
    const int m0 = (swz / gridDim.x) * 64;
    const int n0 = (swz % gridDim.x) * 128;

    f32x4 acc[4][2] = {};

    const int sA = tid;                        // 256 chunks: [kg][row(64)]
    const int s1 = tid, s2 = tid + 256;        // B: 512 chunks: [kg][row(128)]
    const ushort* gA  = &A[(size_t)(m0 + (sA & 63)) * K + (sA >> 6) * 8];
    const ushort* gb1 = &B[(size_t)(n0 + (s1 & 127)) * K + (s1 >> 7) * 8];
    const ushort* gb2 = &B[(size_t)(n0 + (s2 & 127)) * K + (s2 >> 7) * 8];

    const int NT = K / 32;
    gload_lds16(gA,  &As[0][sA * 8]);
    gload_lds16(gb1, &Bs[0][s1 * 8]);
    gload_lds16(gb2, &Bs[0][s2 * 8]);

    for (int t = 0; t < NT; ++t) {
        const int cur = t & 1;
        asm volatile("s_waitcnt vmcnt(0)" ::: "memory");
        __syncthreads();
        if (t + 1 < NT) {
            const int kb = (t + 1) * 32;
            const int nxt = cur ^ 1;
            gload_lds16(gA + kb,  &As[nxt][sA * 8]);
            gload_lds16(gb1 + kb, &Bs[nxt][s1 * 8]);
            gload_lds16(gb2 + kb, &Bs[nxt][s2 * 8]);
        }
        short8 af[4], bf_[2];
#pragma unroll
        for (int m = 0; m < 4; ++m)
            af[m] = *(const short8*)&As[cur][(kgl * 64 + m * 16 + li) * 8];
#pragma unroll
        for (int n = 0; n < 2; ++n)
            bf_[n] = *(const short8*)&Bs[cur][(kgl * 128 + wv * 32 + n * 16 + li) * 8];
#pragma unroll
        for (int m = 0; m < 4; ++m)
#pragma unroll
            for (int n = 0; n < 2; ++n)
                acc[m][n] = __builtin_amdgcn_mfma_f32_16x16x32_bf16(
                    af[m], bf_[n], acc[m][n], 0, 0, 0);
    }

#pragma unroll
    for (int m = 0; m < 4; ++m) {
        const int Rb = m0 + m * 16 + kgl * 4;
#pragma unroll
        for (int n = 0; n < 2; ++n) {
            const int Ncol = n0 + wv * 32 + n * 16 + li;
#pragma unroll
            for (int r = 0; r < 4; ++r)
                C[(size_t)(Rb + r) * N + Ncol] = acc[m][n][r];
        }
    }
}

// ---------------------------------------------------------------------------
// MFMA flash attention, 32x32 swapped form, in-block KV-split (8 waves).
// R7/R12 inner structure (measured optimum) + R14 T1 bijective XCD swizzle
// (FETCH 69.7 -> 12.3 MB verified). Register-capped at 4 waves/SIMD by the
// unified VGPR+AGPR footprint — the documented structural bound (~70 us).
// ---------------------------------------------------------------------------
__global__ __launch_bounds__(512, 4) void attn_mfma(const ushort* __restrict__ Q,
                                                    const ushort* __restrict__ K,
                                                    const ushort* __restrict__ Vt,
                                                    ushort* __restrict__ AO)
{
    __shared__ ushort pool[2][2][2][64 * 64];   // [stream kvh][K/V][buf][8KB]

    const int tid = threadIdx.x, lane = tid & 63, w = tid >> 6;
    const int wq = w & 3, kvh = w >> 2;
    const int r31 = lane & 31, hi = lane >> 5;

    // T1 bijective XCD swizzle (512 blocks, 512 % 8 == 0)
    const int flat = blockIdx.x + gridDim.x * (blockIdx.y + gridDim.y * blockIdx.z);
    const int swzb = (flat & 7) * 64 + (flat >> 3);
    const int q0 = (swzb & 15) * 128;
    const int h = (swzb >> 4) & 15;
    const int b = swzb >> 8;

    const int bh = b * N_HEADS + h;
    const size_t base = (size_t)bh * SEQ * D_K;    // Q, K
    const size_t vbase = (size_t)bh * D_K * SEQ;   // Vt

    // --- probe the permlane32_swap diagonal (wave-uniform) ---
    uint pa = (uint)lane, pbv = 1000u + (uint)lane;
    plswap(pa, pbv);
    const bool swap_lo = (__builtin_amdgcn_readfirstlane(pa) > 500u);

    // Q B-frags: col=q=r31, k(dk) = ks*16 + hi*8 + j
    const size_t qrow = base + (size_t)(q0 + wq * 32 + r31) * D_K;
    short8 qb[4];
#pragma unroll
    for (int ks = 0; ks < 4; ++ks)
        qb[ks] = *(const short8*)&Q[qrow + ks * 16 + hi * 8];

    float m_ = -INFINITY, l_ = 0.f;
    f32x16 o0 = {}, o1 = {};   // O^T: col=q=r31, d = dh*32 + 8*(reg>>2)+4*hi+(reg&3)

    const int srow_l = lane >> 3;   // 0..7
    const int sblk = lane & 7;
    const ushort* Kt0 = &K[base];
    const ushort* Vt0 = &Vt[vbase];
    const int tile0 = kvh * 16;     // this group's first KV tile

    // hoisted lane-constant LDS read offsets (elements)
    const int xr = r31 & 7;
    int off[2][4];
#pragma unroll
    for (int hf = 0; hf < 2; ++hf)
#pragma unroll
        for (int ks = 0; ks < 4; ++ks)
            off[hf][ks] = hf * 2048 + r31 * 64 + (((2 * ks + hi) ^ xr) * 8);

    const ushort* Kst = &pool[kvh][0][0][0];
    const ushort* Vst = &pool[kvh][1][0][0];

#define STAGE(kt_, buf_)                                                       \
    {                                                                          \
        _Pragma("unroll")                                                      \
        for (int p = 0; p < 2; ++p) {                                          \
            const int row = wq * 16 + p * 8 + srow_l;                          \
            const int db = sblk ^ (row & 7);                                   \
            gload_lds16(Kt0 + ((size_t)((tile0 + (kt_)) * 64 + row)) * D_K + db * 8, \
                        &pool[kvh][0][buf_][(wq * 16 + p * 8) * 64]);          \
            gload_lds16(Vt0 + (size_t)row * SEQ + (tile0 + (kt_)) * 64 + db * 8,     \
                        &pool[kvh][1][buf_][(wq * 16 + p * 8) * 64]);          \
        }                                                                      \
    }

    STAGE(0, 0);

    const int NT = SEQ / 64 / 2;    // 16 tiles per group
    for (int kt = 0; kt < NT; ++kt) {
        const int cur = kt & 1;
        asm volatile("s_waitcnt vmcnt(0)" ::: "memory");
        __syncthreads();
        if (kt + 1 < NT) STAGE(kt + 1, cur ^ 1);
        const int cb = cur * 4096;

        // S^T = mfma32(K, Q)
        f32x16 s0 = {}, s1 = {};
        __builtin_amdgcn_s_setprio(1);
#pragma unroll
        for (int ks = 0; ks < 4; ++ks) {
            short8 kb = *(const short8*)(Kst + cb + off[0][ks]);
            s0 = __builtin_amdgcn_mfma_f32_32x32x16_bf16(kb, qb[ks], s0, 0, 0, 0);
        }
#pragma unroll
        for (int ks = 0; ks < 4; ++ks) {
            short8 kb = *(const short8*)(Kst + cb + off[1][ks]);
            s1 = __builtin_amdgcn_mfma_f32_32x32x16_bf16(kb, qb[ks], s1, 0, 0, 0);
        }
        __builtin_amdgcn_s_setprio(0);

        // lane-local row max (31 ops) + 1 shfl across the lane^32 partner
        float mx = fmaxf(s0[0], s0[1]);
#pragma unroll
        for (int e = 2; e < 16; ++e) mx = fmaxf(mx, s0[e]);
#pragma unroll
        for (int e = 0; e < 16; ++e) mx = fmaxf(mx, s1[e]);
        mx = fmaxf(mx, __shfl_xor(mx, 32, 64));

        // defer-max: rescale only when the running max grows by > 8 (log2)
        if (__any(mx > m_ + 8.0f)) {
            const float mn = fmaxf(m_, mx);
            const float sc = exp2f(m_ - mn);
            l_ *= sc;
#pragma unroll
            for (int e = 0; e < 16; ++e) { o0[e] *= sc; o1[e] *= sc; }
            m_ = mn;
        }

        // p = 2^(s - m), tile sum (lane-local + 1 shfl)
        f32x16 p0, p1;
        float ts = 0.f;
#pragma unroll
        for (int e = 0; e < 16; ++e) { p0[e] = exp2f(s0[e] - m_); ts += p0[e]; }
#pragma unroll
        for (int e = 0; e < 16; ++e) { p1[e] = exp2f(s1[e] - m_); ts += p1[e]; }
        ts += __shfl_xor(ts, 32, 64);
        l_ += ts;

        // pack p into bf16-pair dwords (v_cvt_pk_bf16_f32)
        uint u[8][2];
#pragma unroll
        for (int rq = 0; rq < 4; ++rq) {
            u[rq][0]     = cvtpk(p0[4 * rq + 0], p0[4 * rq + 1]);
            u[rq][1]     = cvtpk(p0[4 * rq + 2], p0[4 * rq + 3]);
            u[4 + rq][0] = cvtpk(p1[4 * rq + 0], p1[4 * rq + 1]);
            u[4 + rq][1] = cvtpk(p1[4 * rq + 2], p1[4 * rq + 3]);
        }

        // per k-slice: B-frag = keys octet 2ks (x) + octet 2ks+1 (y), swapped
        short8 pb[4];
#pragma unroll
        for (int ks = 0; ks < 4; ++ks) {
            uint x0 = u[2 * ks][0], x1 = u[2 * ks][1];
            uint y0 = u[2 * ks + 1][0], y1 = u[2 * ks + 1][1];
            if (swap_lo) { plswap(y0, x0); plswap(y1, x1); }
            else         { plswap(x0, y0); plswap(x1, y1); }
            union { uint u4[4]; short8 s; } pu;
            pu.u4[0] = x0; pu.u4[1] = x1; pu.u4[2] = y0; pu.u4[3] = y1;
            pb[ks] = pu.s;
        }

        // O^T += mfma32(Vt, P^T)
        __builtin_amdgcn_s_setprio(1);
#pragma unroll
        for (int ks = 0; ks < 4; ++ks) {
            short8 vb = *(const short8*)(Vst + cb + off[0][ks]);
            o0 = __builtin_amdgcn_mfma_f32_32x32x16_bf16(vb, pb[ks], o0, 0, 0, 0);
        }
#pragma unroll
        for (int ks = 0; ks < 4; ++ks) {
            short8 vb = *(const short8*)(Vst + cb + off[1][ks]);
            o1 = __builtin_amdgcn_mfma_f32_32x32x16_bf16(vb, pb[ks], o1, 0, 0, 0);
        }
        __builtin_amdgcn_s_setprio(0);
    }
#undef STAGE

    // ---- merge the two KV halves through LDS (alias the staging pool) ----
    __syncthreads();
    float* cs = (float*)&pool[0][0][0][0];     // 4 waves * 64 lanes * 32 f = 32KB
    float* ml = cs + 4 * 64 * 32;              // + 512 floats
    const int cidx = (wq * 64 + lane) * 32;
    if (kvh == 1) {
#pragma unroll
        for (int rq = 0; rq < 4; ++rq) {
            f32x4 a, c;
#pragma unroll
            for (int e = 0; e < 4; ++e) { a[e] = o0[4 * rq + e]; c[e] = o1[4 * rq + e]; }
            *(f32x4*)&cs[cidx + 4 * rq] = a;
            *(f32x4*)&cs[cidx + 16 + 4 * rq] = c;
        }
        ml[(wq * 64 + lane) * 2]     = m_;
        ml[(wq * 64 + lane) * 2 + 1] = l_;
    }
    __syncthreads();
    if (kvh == 0) {
        const float m2 = ml[(wq * 64 + lane) * 2];
        const float l2 = ml[(wq * 64 + lane) * 2 + 1];
        const float mM = fmaxf(m_, m2);
        const float sc1 = exp2f(m_ - mM), sc2 = exp2f(m2 - mM);
        const float linv = 1.f / (l_ * sc1 + l2 * sc2);
        ushort* Ao = &AO[((size_t)b * SEQ + q0 + wq * 32 + r31) * D_MODEL + h * 64];
#pragma unroll
        for (int rq = 0; rq < 4; ++rq) {
            f32x4 a = *(const f32x4*)&cs[cidx + 4 * rq];
            f32x4 c = *(const f32x4*)&cs[cidx + 16 + 4 * rq];
            uint2 v0, v1;
            v0.x = cvtpk((o0[4 * rq + 0] * sc1 + a[0] * sc2) * linv,
                         (o0[4 * rq + 1] * sc1 + a[1] * sc2) * linv);
            v0.y = cvtpk((o0[4 * rq + 2] * sc1 + a[2] * sc2) * linv,
                         (o0[4 * rq + 3] * sc1 + a[3] * sc2) * linv);
            v1.x = cvtpk((o1[4 * rq + 0] * sc1 + c[0] * sc2) * linv,
                         (o1[4 * rq + 1] * sc1 + c[1] * sc2) * linv);
            v1.y = cvtpk((o1[4 * rq + 2] * sc1 + c[2] * sc2) * linv,
                         (o1[4 * rq + 3] * sc1 + c[3] * sc2) * linv);
            *(uint2*)&Ao[8 * rq + 4 * hi]      = v0;
            *(uint2*)&Ao[32 + 8 * rq + 4 * hi] = v1;
        }
    }
}

// ---------------------------------------------------------------------------
extern "C" void kernel_launch(void* const* d_in, const int* in_sizes, int n_in,
                              void* d_out, int out_size, void* d_ws, size_t ws_size,
                              hipStream_t stream)
{
    const float* x  = (const float*)d_in[0];
    const float* Wq = (const float*)d_in[1];
    const float* Wk = (const float*)d_in[2];
    const float* Wv = (const float*)d_in[3];
    const float* Wo = (const float*)d_in[4];
    float* out = (float*)d_out;

    ushort* xb   = (ushort*)d_ws;                       // [4096][1024]
    ushort* Wqkv = xb + (size_t)M_TOTAL * D_MODEL;      // [3072][1024]
    ushort* Wob  = Wqkv + (size_t)3 * D_MODEL * D_MODEL;// [1024][1024]
    ushort* q    = Wob + (size_t)D_MODEL * D_MODEL;     // [B,H,S,Dk]
    ushort* k    = q + (size_t)M_TOTAL * D_MODEL;       // [B,H,S,Dk]
    ushort* vt   = k + (size_t)M_TOTAL * D_MODEL;       // [B,H,Dk,S]
    ushort* ao   = vt + (size_t)M_TOTAL * D_MODEL;      // [B,S,D]

    hipLaunchKernelGGL(cast_all, dim3(4096), dim3(256), 0, stream,
                       x, Wq, Wk, Wv, Wo, xb, Wqkv, Wob);

    hipLaunchKernelGGL(gemm_qkv, dim3(3 * D_MODEL / 128, M_TOTAL / 128), dim3(256),
                       0, stream, xb, Wqkv, q, k, vt, M_TOTAL, 3 * D_MODEL, D_MODEL);

    hipLaunchKernelGGL(attn_mfma, dim3(SEQ / 128, N_HEADS, BATCH), dim3(512),
                       0, stream, q, k, vt, ao);

    hipLaunchKernelGGL(gemm_out, dim3(D_MODEL / 128, M_TOTAL / 64), dim3(256),
                       0, stream, ao, Wob, out, M_TOTAL, D_MODEL, D_MODEL);
}

// Round 16
// 154.235 us; speedup vs baseline: 1.0035x; 1.0035x over previous
//
#include <hip/hip_runtime.h>
#include <hip/hip_bf16.h>
#include <math.h>

#define D_MODEL 1024
#define N_HEADS 16
#define D_K     64
#define BATCH   2
#define SEQ     2048
#define M_TOTAL (BATCH * SEQ)   // 4096

typedef __attribute__((ext_vector_type(8))) short short8;    // 8 bf16 = 4 VGPR
typedef __attribute__((ext_vector_type(4))) float f32x4;
typedef __attribute__((ext_vector_type(16))) float f32x16;

__device__ __forceinline__ ushort f2bf(float f) {
    __hip_bfloat16 h = __float2bfloat16(f);
    union { __hip_bfloat16 h; ushort u; } c; c.h = h; return c.u;
}

// packed bf16 convert (RNE on gfx950): lo = cvt(a), hi = cvt(b)
__device__ __forceinline__ uint cvtpk(float a, float b) {
    uint r;
    asm("v_cvt_pk_bf16_f32 %0, %1, %2" : "=v"(r) : "v"(a), "v"(b));
    return r;
}

__device__ __forceinline__ void gload_lds16(const void* g, void* l) {
    __builtin_amdgcn_global_load_lds(
        (const __attribute__((address_space(1))) void*)g,
        (__attribute__((address_space(3))) void*)l, 16, 0, 0);
}

// v_permlane32_swap_b32 vdst, vsrc — exchange diagonal probed at runtime.
__device__ __forceinline__ void plswap(uint& a, uint& b) {
    asm volatile("v_permlane32_swap_b32 %0, %1" : "+v"(a), "+v"(b));
}

// ---------------------------------------------------------------------------
// Fused f32 -> bf16 cast, 8 floats/thread. Wq pre-scaled by 0.125*log2(e)
// (exact fold). ~72 MB of traffic at the BW ceiling.
// ---------------------------------------------------------------------------
__global__ __launch_bounds__(256) void cast_all(const float* __restrict__ x,
                                                const float* __restrict__ Wq,
                                                const float* __restrict__ Wk,
                                                const float* __restrict__ Wv,
                                                const float* __restrict__ Wo,
                                                ushort* __restrict__ xb,
                                                ushort* __restrict__ wqkv,
                                                ushort* __restrict__ wob)
{
    const int bi = blockIdx.x;
    const float* src; ushort* dst; int blk;
    float scale = 1.0f;
    const int NW = D_MODEL * D_MODEL;  // 1M
    if (bi < 2048)      { src = x;  dst = xb;            blk = bi; }
    else if (bi < 2560) { src = Wq; dst = wqkv;          blk = bi - 2048;
                          scale = 0.125f * 1.44269504088896f; }
    else if (bi < 3072) { src = Wk; dst = wqkv + NW;     blk = bi - 2560; }
    else if (bi < 3584) { src = Wv; dst = wqkv + 2 * NW; blk = bi - 3072; }
    else                { src = Wo; dst = wob;           blk = bi - 3584; }
    const int i = blk * 2048 + threadIdx.x * 8;
    float4 a = *(const float4*)&src[i];
    float4 b = *(const float4*)&src[i + 4];
    uint4 o;
    o.x = cvtpk(a.x * scale, a.y * scale);
    o.y = cvtpk(a.z * scale, a.w * scale);
    o.z = cvtpk(b.x * scale, b.y * scale);
    o.w = cvtpk(b.z * scale, b.w * scale);
    *(uint4*)&dst[i] = o;
}

// ---------------------------------------------------------------------------
// QKV GEMM: C = A(M,K) * B(N,K)^T, 128x128 tile, BK=32, 256 thr (4 waves),
// global_load_lds w=16, double-buffered LDS, vmcnt-before-barrier prefetch,
// bijective XCD swizzle. Epilogue (R16): BOTH paths now LDS-coalesced:
//   q/k: acc -> LDS [row][col] bf16 (32 KB exact fit, (row>>2)&7 XOR ->
//        conflict-free writes), then full-row dwordx4 reads -> contiguous
//        [s][dk] slab stores (100% sector utilization, was ~50%).
//   v:   acc -> LDS [col][row] bf16 -> coalesced dwordx4 to [B,H,Dk,S].
// ---------------------------------------------------------------------------
__global__ __launch_bounds__(256) void gemm_qkv(const ushort* __restrict__ A,
                                                const ushort* __restrict__ B,
                                                ushort* __restrict__ q,
                                                ushort* __restrict__ k,
                                                ushort* __restrict__ v,
                                                int M, int N, int K)
{
    __shared__ ushort SH[16384];   // As = SH[0..8191] (2 bufs), Bs = SH[8192..]

    const int tid = threadIdx.x;
    const int lane = tid & 63;
    const int w = tid >> 6;
    const int li = lane & 15;
    const int kgl = lane >> 4;

    // XCD-aware bijective swizzle (nwg % 8 == 0)
    const int nwg = gridDim.x * gridDim.y;
    const int flat = blockIdx.y * gridDim.x + blockIdx.x;
    const int cpx = nwg >> 3;
    const int swz = (flat & 7) * cpx + (flat >> 3);
    const int m0 = (swz / gridDim.x) * 128;
    const int n0 = (swz % gridDim.x) * 128;

    const int wr = (w >> 1) * 64;
    const int wc = (w & 1) * 64;

    f32x4 acc[4][4] = {};

    const int s1 = tid, s2 = tid + 256;
    const ushort* ga1 = &A[(size_t)(m0 + (s1 & 127)) * K + (s1 >> 7) * 8];
    const ushort* ga2 = &A[(size_t)(m0 + (s2 & 127)) * K + (s2 >> 7) * 8];
    const ushort* gb1 = &B[(size_t)(n0 + (s1 & 127)) * K + (s1 >> 7) * 8];
    const ushort* gb2 = &B[(size_t)(n0 + (s2 & 127)) * K + (s2 >> 7) * 8];

    const int NT = K / 32;
    gload_lds16(ga1, &SH[0 + s1 * 8]);
    gload_lds16(ga2, &SH[0 + s2 * 8]);
    gload_lds16(gb1, &SH[8192 + s1 * 8]);
    gload_lds16(gb2, &SH[8192 + s2 * 8]);

    for (int t = 0; t < NT; ++t) {
        const int cur = t & 1;
        asm volatile("s_waitcnt vmcnt(0)" ::: "memory");
        __syncthreads();
        if (t + 1 < NT) {
            const int kb = (t + 1) * 32;
            const int nxt = cur ^ 1;
            gload_lds16(ga1 + kb, &SH[nxt * 4096 + s1 * 8]);
            gload_lds16(ga2 + kb, &SH[nxt * 4096 + s2 * 8]);
            gload_lds16(gb1 + kb, &SH[8192 + nxt * 4096 + s1 * 8]);
            gload_lds16(gb2 + kb, &SH[8192 + nxt * 4096 + s2 * 8]);
        }
        short8 af[4], bf_[4];
#pragma unroll
        for (int m = 0; m < 4; ++m)
            af[m] = *(const short8*)&SH[cur * 4096 + (kgl * 128 + wr + m * 16 + li) * 8];
#pragma unroll
        for (int n = 0; n < 4; ++n)
            bf_[n] = *(const short8*)&SH[8192 + cur * 4096 + (kgl * 128 + wc + n * 16 + li) * 8];
#pragma unroll
        for (int m = 0; m < 4; ++m)
#pragma unroll
            for (int n = 0; n < 4; ++n)
                acc[m][n] = __builtin_amdgcn_mfma_f32_16x16x32_bf16(
                    af[m], bf_[n], acc[m][n], 0, 0, 0);
    }

    if (n0 < 2048) {
        // q/k: LDS round-trip for fully coalesced stores.
        ushort* const dst = (n0 < 1024) ? q : k;
        __syncthreads();   // all waves done with K-loop LDS reads
        // write C tile [row][col] bf16 into SH (32 KB exact). XOR bits 5-7
        // with (row>>2)&7: the 4 kgl-rows of one store land in 4 distinct
        // 32B blocks -> 64 lanes cover 128B -> conflict-free.
#pragma unroll
        for (int m = 0; m < 4; ++m) {
#pragma unroll
            for (int n = 0; n < 4; ++n) {
                const int col = wc + n * 16 + li;
#pragma unroll
                for (int r = 0; r < 4; ++r) {
                    const int row = wr + m * 16 + kgl * 4 + r;
                    const int byte = (row * 256 + col * 2) ^ (((row >> 2) & 7) << 5);
                    *(ushort*)((char*)SH + byte) = f2bf(acc[m][n][r]);
                }
            }
        }
        __syncthreads();
        // read 16B chunks (row, chunk) and store contiguous [s][dk] slabs.
        const int b = m0 >> 11, s0 = m0 & 2047;
#pragma unroll
        for (int it = 0; it < 8; ++it) {
            const int item = it * 256 + tid;
            const int row = item >> 4;            // 0..127
            const int chunk = item & 15;          // 16B = 8 cols
            const int byte = (row * 256 + chunk * 16) ^ (((row >> 2) & 7) << 5);
            uint4 val = *(uint4*)((char*)SH + byte);
            const int rem = (n0 & 1023) + chunk * 8;
            const int h = rem >> 6, dk = rem & 63;
            ushort* p = dst + ((size_t)(b * N_HEADS + h) * SEQ + s0 + row) * D_K + dk;
            *(uint4*)p = val;
        }
    } else {
        // v: LDS transpose (reuse the 32KB staging pool) + coalesced stores
        __syncthreads();   // all waves done with K-loop LDS reads
#pragma unroll
        for (int m = 0; m < 4; ++m) {
            const int row0 = wr + m * 16 + kgl * 4;   // local C row (s)
#pragma unroll
            for (int n = 0; n < 4; ++n) {
                const int col = wc + n * 16 + li;     // local C col (dk')
                uint2 pv;
                pv.x = cvtpk(acc[m][n][0], acc[m][n][1]);
                pv.y = cvtpk(acc[m][n][2], acc[m][n][3]);
                const int byte = (col * 256 + row0 * 2) ^ ((col & 7) << 5);
                *(uint2*)((char*)SH + byte) = pv;
            }
        }
        __syncthreads();
        const int b = m0 >> 11, s0 = m0 & 2047;
        const int lsl = tid & 15;       // s sub-chunk (16B)
        const int crow = tid >> 4;      // 0..15
#pragma unroll
        for (int it = 0; it < 8; ++it) {
            const int c = it * 16 + crow;                 // local col (dk')
            const int rem = (n0 & 1023) + c;
            const int h = rem >> 6, dk = rem & 63;
            const int byte = (c * 256 + lsl * 16) ^ ((c & 7) << 5);
            uint4 val = *(uint4*)((char*)SH + byte);
            ushort* vp = v + ((size_t)(b * N_HEADS + h) * D_K + dk) * SEQ + s0 + lsl * 8;
            *(uint4*)vp = val;
        }
    }
}

// ---------------------------------------------------------------------------
// Output GEMM: C(fp32) = A(M,K) * B(N,K)^T. 64x128 tile, BK=32, 256 thr
// (4 waves of 64x32): grid 8x64 = 512 blocks = 2 blocks/CU. Stores are
// 4x64B full sectors — already efficient, left unchanged.
// ---------------------------------------------------------------------------
__global__ __launch_bounds__(256) void gemm_out(const ushort* __restrict__ A,
                                                const ushort* __restrict__ B,
                                                float* __restrict__ C,
                                                int M, int N, int K)
{
    __shared__ ushort As[2][4 * 64 * 8];     // 4 KB per buf
    __shared__ ushort Bs[2][4 * 128 * 8];    // 8 KB per buf

    const int tid = threadIdx.x;
    const int lane = tid & 63;
    const int wv = tid >> 6;          // wave 0..3 -> n-col strip of 32
    const int li = lane & 15;
    const int kgl = lane >> 4;

    const int nwg = gridDim.x * gridDim.y;
    const int flat = blockIdx.y * gridDim.x + blockIdx.x;
    const int cpx = nwg >> 3;
    const int swz = (flat & 7) * cpx + (flat >> 3);
    const int m0 = (swz / gridDim.x) * 64;
    const int n0 = (swz % gridDim.x) * 128;

    f32x4 acc[4][2] = {};

    const int sA = tid;                        // 256 chunks: [kg][row(64)]
    const int s1 = tid, s2 = tid + 256;        // B: 512 chunks: [kg][row(128)]
    const ushort* gA  = &A[(size_t)(m0 + (sA & 63)) * K + (sA >> 6) * 8];
    const ushort* gb1 = &B[(size_t)(n0 + (s1 & 127)) * K + (s1 >> 7) * 8];
    const ushort* gb2 = &B[(size_t)(n0 + (s2 & 127)) * K + (s2 >> 7) * 8];

    const int NT = K / 32;
    gload_lds16(gA,  &As[0][sA * 8]);
    gload_lds16(gb1, &Bs[0][s1 * 8]);
    gload_lds16(gb2, &Bs[0][s2 * 8]);

    for (int t = 0; t < NT; ++t) {
        const int cur = t & 1;
        asm volatile("s_waitcnt vmcnt(0)" ::: "memory");
        __syncthreads();
        if (t + 1 < NT) {
            const int kb = (t + 1) * 32;
            const int nxt = cur ^ 1;
            gload_lds16(gA + kb,  &As[nxt][sA * 8]);
            gload_lds16(gb1 + kb, &Bs[nxt][s1 * 8]);
            gload_lds16(gb2 + kb, &Bs[nxt][s2 * 8]);
        }
        short8 af[4], bf_[2];
#pragma unroll
        for (int m = 0; m < 4; ++m)
            af[m] = *(const short8*)&As[cur][(kgl * 64 + m * 16 + li) * 8];
#pragma unroll
        for (int n = 0; n < 2; ++n)
            bf_[n] = *(const short8*)&Bs[cur][(kgl * 128 + wv * 32 + n * 16 + li) * 8];
#pragma unroll
        for (int m = 0; m < 4; ++m)
#pragma unroll
            for (int n = 0; n < 2; ++n)
                acc[m][n] = __builtin_amdgcn_mfma_f32_16x16x32_bf16(
                    af[m], bf_[n], acc[m][n], 0, 0, 0);
    }

#pragma unroll
    for (int m = 0; m < 4; ++m) {
        const int Rb = m0 + m * 16 + kgl * 4;
#pragma unroll
        for (int n = 0; n < 2; ++n) {
            const int Ncol = n0 + wv * 32 + n * 16 + li;
#pragma unroll
            for (int r = 0; r < 4; ++r)
                C[(size_t)(Rb + r) * N + Ncol] = acc[m][n][r];
        }
    }
}

// ---------------------------------------------------------------------------
// MFMA flash attention, 32x32 swapped form, in-block KV-split (8 waves).
// R7/R12 inner structure (measured optimum) + T1 bijective XCD swizzle
// (FETCH 69.7 -> 12.3 MB verified; time unchanged -> serial-chain-bound at
// the unified-register-file cap of 4 waves/SIMD). Unchanged.
// ---------------------------------------------------------------------------
__global__ __launch_bounds__(512, 4) void attn_mfma(const ushort* __restrict__ Q,
                                                    const ushort* __restrict__ K,
                                                    const ushort* __restrict__ Vt,
                                                    ushort* __restrict__ AO)
{
    __shared__ ushort pool[2][2][2][64 * 64];   // [stream kvh][K/V][buf][8KB]

    const int tid = threadIdx.x, lane = tid & 63, w = tid >> 6;
    const int wq = w & 3, kvh = w >> 2;
    const int r31 = lane & 31, hi = lane >> 5;

    // T1 bijective XCD swizzle (512 blocks, 512 % 8 == 0)
    const int flat = blockIdx.x + gridDim.x * (blockIdx.y + gridDim.y * blockIdx.z);
    const int swzb = (flat & 7) * 64 + (flat >> 3);
    const int q0 = (swzb & 15) * 128;
    const int h = (swzb >> 4) & 15;
    const int b = swzb >> 8;

    const int bh = b * N_HEADS + h;
    const size_t base = (size_t)bh * SEQ * D_K;    // Q, K
    const size_t vbase = (size_t)bh * D_K * SEQ;   // Vt

    // --- probe the permlane32_swap diagonal (wave-uniform) ---
    uint pa = (uint)lane, pbv = 1000u + (uint)lane;
    plswap(pa, pbv);
    const bool swap_lo = (__builtin_amdgcn_readfirstlane(pa) > 500u);

    // Q B-frags: col=q=r31, k(dk) = ks*16 + hi*8 + j
    const size_t qrow = base + (size_t)(q0 + wq * 32 + r31) * D_K;
    short8 qb[4];
#pragma unroll
    for (int ks = 0; ks < 4; ++ks)
        qb[ks] = *(const short8*)&Q[qrow + ks * 16 + hi * 8];

    float m_ = -INFINITY, l_ = 0.f;
    f32x16 o0 = {}, o1 = {};   // O^T: col=q=r31, d = dh*32 + 8*(reg>>2)+4*hi+(reg&3)

    const int srow_l = lane >> 3;   // 0..7
    const int sblk = lane & 7;
    const ushort* Kt0 = &K[base];
    const ushort* Vt0 = &Vt[vbase];
    const int tile0 = kvh * 16;     // this group's first KV tile

    // hoisted lane-constant LDS read offsets (elements)
    const int xr = r31 & 7;
    int off[2][4];
#pragma unroll
    for (int hf = 0; hf < 2; ++hf)
#pragma unroll
        for (int ks = 0; ks < 4; ++ks)
            off[hf][ks] = hf * 2048 + r31 * 64 + (((2 * ks + hi) ^ xr) * 8);

    const ushort* Kst = &pool[kvh][0][0][0];
    const ushort* Vst = &pool[kvh][1][0][0];

#define STAGE(kt_, buf_)                                                       \
    {                                                                          \
        _Pragma("unroll")                                                      \
        for (int p = 0; p < 2; ++p) {                                          \
            const int row = wq * 16 + p * 8 + srow_l;                          \
            const int db = sblk ^ (row & 7);                                   \
            gload_lds16(Kt0 + ((size_t)((tile0 + (kt_)) * 64 + row)) * D_K + db * 8, \
                        &pool[kvh][0][buf_][(wq * 16 + p * 8) * 64]);          \
            gload_lds16(Vt0 + (size_t)row * SEQ + (tile0 + (kt_)) * 64 + db * 8,     \
                        &pool[kvh][1][buf_][(wq * 16 + p * 8) * 64]);          \
        }                                                                      \
    }

    STAGE(0, 0);

    const int NT = SEQ / 64 / 2;    // 16 tiles per group
    for (int kt = 0; kt < NT; ++kt) {
        const int cur = kt & 1;
        asm volatile("s_waitcnt vmcnt(0)" ::: "memory");
        __syncthreads();
        if (kt + 1 < NT) STAGE(kt + 1, cur ^ 1);
        const int cb = cur * 4096;

        // S^T = mfma32(K, Q)
        f32x16 s0 = {}, s1 = {};
        __builtin_amdgcn_s_setprio(1);
#pragma unroll
        for (int ks = 0; ks < 4; ++ks) {
            short8 kb = *(const short8*)(Kst + cb + off[0][ks]);
            s0 = __builtin_amdgcn_mfma_f32_32x32x16_bf16(kb, qb[ks], s0, 0, 0, 0);
        }
#pragma unroll
        for (int ks = 0; ks < 4; ++ks) {
            short8 kb = *(const short8*)(Kst + cb + off[1][ks]);
            s1 = __builtin_amdgcn_mfma_f32_32x32x16_bf16(kb, qb[ks], s1, 0, 0, 0);
        }
        __builtin_amdgcn_s_setprio(0);

        // lane-local row max (31 ops) + 1 shfl across the lane^32 partner
        float mx = fmaxf(s0[0], s0[1]);
#pragma unroll
        for (int e = 2; e < 16; ++e) mx = fmaxf(mx, s0[e]);
#pragma unroll
        for (int e = 0; e < 16; ++e) mx = fmaxf(mx, s1[e]);
        mx = fmaxf(mx, __shfl_xor(mx, 32, 64));

        // defer-max: rescale only when the running max grows by > 8 (log2)
        if (__any(mx > m_ + 8.0f)) {
            const float mn = fmaxf(m_, mx);
            const float sc = exp2f(m_ - mn);
            l_ *= sc;
#pragma unroll
            for (int e = 0; e < 16; ++e) { o0[e] *= sc; o1[e] *= sc; }
            m_ = mn;
        }

        // p = 2^(s - m), tile sum (lane-local + 1 shfl)
        f32x16 p0, p1;
        float ts = 0.f;
#pragma unroll
        for (int e = 0; e < 16; ++e) { p0[e] = exp2f(s0[e] - m_); ts += p0[e]; }
#pragma unroll
        for (int e = 0; e < 16; ++e) { p1[e] = exp2f(s1[e] - m_); ts += p1[e]; }
        ts += __shfl_xor(ts, 32, 64);
        l_ += ts;

        // pack p into bf16-pair dwords (v_cvt_pk_bf16_f32)
        uint u[8][2];
#pragma unroll
        for (int rq = 0; rq < 4; ++rq) {
            u[rq][0]     = cvtpk(p0[4 * rq + 0], p0[4 * rq + 1]);
            u[rq][1]     = cvtpk(p0[4 * rq + 2], p0[4 * rq + 3]);
            u[4 + rq][0] = cvtpk(p1[4 * rq + 0], p1[4 * rq + 1]);
            u[4 + rq][1] = cvtpk(p1[4 * rq + 2], p1[4 * rq + 3]);
        }

        // per k-slice: B-frag = keys octet 2ks (x) + octet 2ks+1 (y), swapped
        short8 pb[4];
#pragma unroll
        for (int ks = 0; ks < 4; ++ks) {
            uint x0 = u[2 * ks][0], x1 = u[2 * ks][1];
            uint y0 = u[2 * ks + 1][0], y1 = u[2 * ks + 1][1];
            if (swap_lo) { plswap(y0, x0); plswap(y1, x1); }
            else         { plswap(x0, y0); plswap(x1, y1); }
            union { uint u4[4]; short8 s; } pu;
            pu.u4[0] = x0; pu.u4[1] = x1; pu.u4[2] = y0; pu.u4[3] = y1;
            pb[ks] = pu.s;
        }

        // O^T += mfma32(Vt, P^T)
        __builtin_amdgcn_s_setprio(1);
#pragma unroll
        for (int ks = 0; ks < 4; ++ks) {
            short8 vb = *(const short8*)(Vst + cb + off[0][ks]);
            o0 = __builtin_amdgcn_mfma_f32_32x32x16_bf16(vb, pb[ks], o0, 0, 0, 0);
        }
#pragma unroll
        for (int ks = 0; ks < 4; ++ks) {
            short8 vb = *(const short8*)(Vst + cb + off[1][ks]);
            o1 = __builtin_amdgcn_mfma_f32_32x32x16_bf16(vb, pb[ks], o1, 0, 0, 0);
        }
        __builtin_amdgcn_s_setprio(0);
    }
#undef STAGE

    // ---- merge the two KV halves through LDS (alias the staging pool) ----
    __syncthreads();
    float* cs = (float*)&pool[0][0][0][0];     // 4 waves * 64 lanes * 32 f = 32KB
    float* ml = cs + 4 * 64 * 32;              // + 512 floats
    const int cidx = (wq * 64 + lane) * 32;
    if (kvh == 1) {
#pragma unroll
        for (int rq = 0; rq < 4; ++rq) {
            f32x4 a, c;
#pragma unroll
            for (int e = 0; e < 4; ++e) { a[e] = o0[4 * rq + e]; c[e] = o1[4 * rq + e]; }
            *(f32x4*)&cs[cidx + 4 * rq] = a;
            *(f32x4*)&cs[cidx + 16 + 4 * rq] = c;
        }
        ml[(wq * 64 + lane) * 2]     = m_;
        ml[(wq * 64 + lane) * 2 + 1] = l_;
    }
    __syncthreads();
    if (kvh == 0) {
        const float m2 = ml[(wq * 64 + lane) * 2];
        const float l2 = ml[(wq * 64 + lane) * 2 + 1];
        const float mM = fmaxf(m_, m2);
        const float sc1 = exp2f(m_ - mM), sc2 = exp2f(m2 - mM);
        const float linv = 1.f / (l_ * sc1 + l2 * sc2);
        ushort* Ao = &AO[((size_t)b * SEQ + q0 + wq * 32 + r31) * D_MODEL + h * 64];
#pragma unroll
        for (int rq = 0; rq < 4; ++rq) {
            f32x4 a = *(const f32x4*)&cs[cidx + 4 * rq];
            f32x4 c = *(const f32x4*)&cs[cidx + 16 + 4 * rq];
            uint2 v0, v1;
            v0.x = cvtpk((o0[4 * rq + 0] * sc1 + a[0] * sc2) * linv,
                         (o0[4 * rq + 1] * sc1 + a[1] * sc2) * linv);
            v0.y = cvtpk((o0[4 * rq + 2] * sc1 + a[2] * sc2) * linv,
                         (o0[4 * rq + 3] * sc1 + a[3] * sc2) * linv);
            v1.x = cvtpk((o1[4 * rq + 0] * sc1 + c[0] * sc2) * linv,
                         (o1[4 * rq + 1] * sc1 + c[1] * sc2) * linv);
            v1.y = cvtpk((o1[4 * rq + 2] * sc1 + c[2] * sc2) * linv,
                         (o1[4 * rq + 3] * sc1 + c[3] * sc2) * linv);
            *(uint2*)&Ao[8 * rq + 4 * hi]      = v0;
            *(uint2*)&Ao[32 + 8 * rq + 4 * hi] = v1;
        }
    }
}

// ---------------------------------------------------------------------------
extern "C" void kernel_launch(void* const* d_in, const int* in_sizes, int n_in,
                              void* d_out, int out_size, void* d_ws, size_t ws_size,
                              hipStream_t stream)
{
    const float* x  = (const float*)d_in[0];
    const float* Wq = (const float*)d_in[1];
    const float* Wk = (const float*)d_in[2];
    const float* Wv = (const float*)d_in[3];
    const float* Wo = (const float*)d_in[4];
    float* out = (float*)d_out;

    ushort* xb   = (ushort*)d_ws;                       // [4096][1024]
    ushort* Wqkv = xb + (size_t)M_TOTAL * D_MODEL;      // [3072][1024]
    ushort* Wob  = Wqkv + (size_t)3 * D_MODEL * D_MODEL;// [1024][1024]
    ushort* q    = Wob + (size_t)D_MODEL * D_MODEL;     // [B,H,S,Dk]
    ushort* k    = q + (size_t)M_TOTAL * D_MODEL;       // [B,H,S,Dk]
    ushort* vt   = k + (size_t)M_TOTAL * D_MODEL;       // [B,H,Dk,S]
    ushort* ao   = vt + (size_t)M_TOTAL * D_MODEL;      // [B,S,D]

    hipLaunchKernelGGL(cast_all, dim3(4096), dim3(256), 0, stream,
                       x, Wq, Wk, Wv, Wo, xb, Wqkv, Wob);

    hipLaunchKernelGGL(gemm_qkv, dim3(3 * D_MODEL / 128, M_TOTAL / 128), dim3(256),
                       0, stream, xb, Wqkv, q, k, vt, M_TOTAL, 3 * D_MODEL, D_MODEL);

    hipLaunchKernelGGL(attn_mfma, dim3(SEQ / 128, N_HEADS, BATCH), dim3(512),
                       0, stream, q, k, vt, ao);

    hipLaunchKernelGGL(gemm_out, dim3(D_MODEL / 128, M_TOTAL / 64), dim3(256),
                       0, stream, ao, Wob, out, M_TOTAL, D_MODEL, D_MODEL);
}